// Round 1
// 725.924 us; speedup vs baseline: 1.1938x; 1.1938x over previous
//
#include <hip/hip_runtime.h>
#include <stdint.h>

// BinHD: samples [8192,10000] f32 {0,1}, classes [1000,10000] f32 {0,1}
// out [8192,1000] f32 = exact Hamming distance via popcount(xor) on bit-packed rows.
#define N_ROWS 8192
#define C_CLS  1000
#define D_DIM  10000
#define W64P   160            // u64 words per packed row (157.x used, rest zero)
#define W32P   (W64P * 2)     // 320 u32 words per packed row
#define KW     32             // u32 words per K-chunk (128 B per row per chunk)
#define NCHUNK 10             // 10 * 32 = 320 words

// ---------------------------------------------------------------------------
// Kernel 1: bit-pack fp32 {0,1} rows into u64 words, float4 + 4 ballots/iter.
// Bit order: dim d -> word (d/256)*4 + (d%4), bit (d%256)/4.  This is a fixed
// permutation applied identically to samples and classes, so popc(xor) is
// unchanged (Hamming distance is permutation-invariant). Writes ALL 160 words
// per row (padding dims compare false -> 0 bits), fully initializing the
// poisoned workspace region we later read.
// ---------------------------------------------------------------------------
__global__ __launch_bounds__(256) void pack_kernel(
    const float* __restrict__ samples, const float* __restrict__ classes,
    unsigned long long* __restrict__ pA, unsigned long long* __restrict__ pB)
{
    int gwave = (blockIdx.x * 256 + threadIdx.x) >> 6;
    int lane  = threadIdx.x & 63;
    if (gwave >= N_ROWS + C_CLS) return;   // wave-uniform exit

    const float* src;
    unsigned long long* dst;
    if (gwave < N_ROWS) {
        src = samples + (size_t)gwave * D_DIM;
        dst = pA + (size_t)gwave * W64P;
    } else {
        int r = gwave - N_ROWS;
        src = classes + (size_t)r * D_DIM;
        dst = pB + (size_t)r * W64P;
    }

    #pragma unroll 4
    for (int w = 0; w < 40; ++w) {         // 40 * 4 = 160 u64 words
        int idx = w * 256 + lane * 4;      // float index; 16B per lane, coalesced 1KB/wave
        float4 v = make_float4(0.f, 0.f, 0.f, 0.f);
        if (idx < D_DIM) v = *(const float4*)(src + idx);   // D_DIM%4==0 -> no partial vec
        unsigned long long m0 = __ballot(v.x > 0.5f);
        unsigned long long m1 = __ballot(v.y > 0.5f);
        unsigned long long m2 = __ballot(v.z > 0.5f);
        unsigned long long m3 = __ballot(v.w > 0.5f);
        if (lane == 0) {
            uint4 p0, p1;
            p0.x = (uint32_t)m0; p0.y = (uint32_t)(m0 >> 32);
            p0.z = (uint32_t)m1; p0.w = (uint32_t)(m1 >> 32);
            p1.x = (uint32_t)m2; p1.y = (uint32_t)(m2 >> 32);
            p1.z = (uint32_t)m3; p1.w = (uint32_t)(m3 >> 32);
            *(uint4*)(dst + (size_t)w * 4)     = p0;
            *(uint4*)(dst + (size_t)w * 4 + 2) = p1;
        }
    }
}

// ---------------------------------------------------------------------------
// Kernel 2: Hamming "GEMM": out[n,c] = sum_w popc(A[n,w] ^ B[c,w]).
// 128x128 tile, 256 threads, 8x8 accs/thread. K in 10 chunks of 32 u32 words.
// Double-buffered LDS filled by global_load_lds DMA (no staging regs, no
// ds_writes), ONE barrier per chunk (T3 minimum-2-phase pattern):
//    STAGE(ch+1 -> buf^1); compute(buf); __syncthreads(); // vmcnt drain here
// Swizzle (rule #21, both-sides): LDS dest is linear (HW requirement); the
// per-lane GLOBAL source address carries the XOR (gsrc = (lane&7)^key,
// key=(row>>3)&7), and ds_reads apply the same XOR -> A reads, B reads and
// DMA writes are all bank-conflict-free. B stored row-major like A (no
// transpose scatter). B tail: source col clamped to 999; those accumulators
// map to out cols >= 1000 which the epilogue never stores.
// ---------------------------------------------------------------------------
__global__ __launch_bounds__(256) void hd_kernel(
    const uint32_t* __restrict__ pA, const uint32_t* __restrict__ pB,
    float* __restrict__ out)
{
    __shared__ uint32_t As[2][128 * KW];   // 2 x 16 KB
    __shared__ uint32_t Bs[2][128 * KW];   // 2 x 16 KB  (total 64 KB, 2 blocks/CU)

    const int tid  = threadIdx.x;
    const int row0 = blockIdx.x * 128;     // 64 row tiles
    const int col0 = blockIdx.y * 128;     // 8 col tiles (1024 padded cols)

    const int w    = tid >> 6;             // wave 0..3
    const int lane = tid & 63;
    const int lx   = lane & 7;             // col octet within wave tile
    const int ly   = lane >> 3;            // row octet within wave tile
    const int wx   = w & 1, wy = w >> 1;
    const int trow = wy * 64 + ly * 8;     // thread row base in 128-tile
    const int tcol = wx * 64 + lx * 8;     // thread col base in 128-tile

    // Per-lane DMA source pointers, pre-swizzled; LDS bases are wave-uniform.
    // Span sp = w + 4*i covers rows [8*sp, 8*sp+7]; each wave stages 1KB/instr.
    const uint32_t* gA[4];
    const uint32_t* gB[4];
    uint32_t*       lA[4];
    uint32_t*       lB[4];
    #pragma unroll
    for (int i = 0; i < 4; ++i) {
        int sp   = w + 4 * i;              // 0..15, bijective over (w,i)
        int key  = sp & 7;
        int rr   = sp * 8 + (lane >> 3);   // row within 128-tile
        int gsrc = (lane & 7) ^ key;       // pre-swizzled 16B-group
        gA[i] = pA + (size_t)(row0 + rr) * W32P + gsrc * 4;
        int gc = col0 + rr;
        if (gc >= C_CLS) gc = C_CLS - 1;   // clamp: results for cols>=1000 discarded
        gB[i] = pB + (size_t)gc * W32P + gsrc * 4;
        lA[i] = &As[0][sp * 256];          // + buf*4096 selects buffer
        lB[i] = &Bs[0][sp * 256];
    }

#define STAGE(ch, buf) do {                                                        \
    _Pragma("unroll")                                                              \
    for (int i = 0; i < 4; ++i) {                                                  \
        __builtin_amdgcn_global_load_lds(                                          \
            (const __attribute__((address_space(1))) uint32_t*)(gA[i] + (ch) * KW),\
            (__attribute__((address_space(3))) uint32_t*)(lA[i] + (buf) * 4096),   \
            16, 0, 0);                                                             \
        __builtin_amdgcn_global_load_lds(                                          \
            (const __attribute__((address_space(1))) uint32_t*)(gB[i] + (ch) * KW),\
            (__attribute__((address_space(3))) uint32_t*)(lB[i] + (buf) * 4096),   \
            16, 0, 0);                                                             \
    }                                                                              \
} while (0)

    uint32_t acc[8][8];
    #pragma unroll
    for (int r = 0; r < 8; ++r)
        #pragma unroll
        for (int c = 0; c < 8; ++c) acc[r][c] = 0;

    STAGE(0, 0);
    __syncthreads();                        // drain chunk-0 DMA

    for (int ch = 0; ch < NCHUNK; ++ch) {   // NOT unrolled: keep body in I-cache
        const int cur = ch & 1;
        if (ch + 1 < NCHUNK) STAGE(ch + 1, cur ^ 1);   // async, hides under compute

        const uint32_t* Ab = &As[0][0] + cur * (128 * KW);
        const uint32_t* Bb = &Bs[0][0] + cur * (128 * KW);

        #pragma unroll
        for (int g = 0; g < 8; ++g) {       // 16B sub-group of the 128B chunk-row
            uint4 a[8], b[8];
            #pragma unroll
            for (int r = 0; r < 8; ++r)     // banks 4*(g^ly): conflict-free, lx bcast
                a[r] = *(const uint4*)&Ab[(trow + r) * KW + ((g ^ ly) << 2)];
            #pragma unroll
            for (int c = 0; c < 8; ++c)     // banks 4*(g^lx): conflict-free, ly bcast
                b[c] = *(const uint4*)&Bb[(tcol + c) * KW + ((g ^ lx) << 2)];
            #pragma unroll
            for (int r = 0; r < 8; ++r)
                #pragma unroll
                for (int c = 0; c < 8; ++c) {
                    acc[r][c] += __popc(a[r].x ^ b[c].x);
                    acc[r][c] += __popc(a[r].y ^ b[c].y);
                    acc[r][c] += __popc(a[r].z ^ b[c].z);
                    acc[r][c] += __popc(a[r].w ^ b[c].w);
                }
        }
        __syncthreads();   // vmcnt(0)+barrier: next-chunk DMA done, cur reads done
    }
#undef STAGE

    // ---- epilogue: exact integer -> f32, float4 stores (1000 % 4 == 0) ----
    #pragma unroll
    for (int r = 0; r < 8; ++r) {
        int grow = row0 + trow + r;
        #pragma unroll
        for (int c4 = 0; c4 < 2; ++c4) {
            int gcol = col0 + tcol + c4 * 4;
            if (gcol < C_CLS) {
                float4 v = make_float4((float)acc[r][c4 * 4 + 0],
                                       (float)acc[r][c4 * 4 + 1],
                                       (float)acc[r][c4 * 4 + 2],
                                       (float)acc[r][c4 * 4 + 3]);
                *(float4*)(out + (size_t)grow * C_CLS + gcol) = v;
            }
        }
    }
}

extern "C" void kernel_launch(void* const* d_in, const int* in_sizes, int n_in,
                              void* d_out, int out_size, void* d_ws, size_t ws_size,
                              hipStream_t stream) {
    const float* samples = (const float*)d_in[0];   // [8192, 10000] f32
    const float* classes = (const float*)d_in[1];   // [1000, 10000] f32
    float* out = (float*)d_out;                     // [8192, 1000] f32

    // Workspace layout: packed A (8192*160 u64 = 10.49 MB) then packed B (1.28 MB)
    unsigned long long* pA = (unsigned long long*)d_ws;
    unsigned long long* pB = pA + (size_t)N_ROWS * W64P;

    int waves  = N_ROWS + C_CLS;             // one wave per row
    int blocks = (waves + 3) / 4;            // 4 waves per 256-thread block
    pack_kernel<<<blocks, 256, 0, stream>>>(samples, classes, pA, pB);

    dim3 grid(N_ROWS / 128, 8);              // 64 x 8 = 512 blocks (2 per CU)
    hd_kernel<<<grid, 256, 0, stream>>>((const uint32_t*)pA, (const uint32_t*)pB, out);
}